// Round 5
// baseline (147.363 us; speedup 1.0000x reference)
//
#include <hip/hip_runtime.h>
#include <math.h>

#define EPS 1e-5f

constexpr int Bc = 64, Pc = 68, Hc = 64, Wc = 64;
constexpr int NPIX  = Hc * Wc;   // 4096 pixels per tile
constexpr int NTILE = Bc * Pc;   // 4352 tiles
constexpr int BLK   = 256;       // threads per block
constexpr int PPT   = NPIX / BLK; // 16 pixels per thread

// Block-wide sum reduction (256 threads = 4 waves of 64).
__device__ __forceinline__ float block_reduce_sum(float v, float* sbuf) {
    __syncthreads();  // protect sbuf / order prior LDS writes
    #pragma unroll
    for (int o = 32; o > 0; o >>= 1) v += __shfl_down(v, o, 64);
    const int lane = threadIdx.x & 63;
    const int wid  = threadIdx.x >> 6;
    if (lane == 0) sbuf[wid] = v;
    __syncthreads();
    if (threadIdx.x == 0) {
        sbuf[4] = sbuf[0] + sbuf[1] + sbuf[2] + sbuf[3];
    }
    __syncthreads();
    return sbuf[4];
}

__global__ __launch_bounds__(BLK)
void gauss_kld_kernel(const float* __restrict__ hm,
                      const float* __restrict__ means,
                      const float* __restrict__ cov,
                      float* __restrict__ out) {
    __shared__ float e_lds[NPIX];   // 16 KB: exp(lp) per pixel, computed once
    __shared__ float sbuf[8];

    const int tile = blockIdx.x;
    const float* __restrict__ h = hm + (size_t)tile * NPIX;
    const int t = threadIdx.x;

    const float mx  = means[tile * 2 + 0];
    const float my  = means[tile * 2 + 1];
    const float s00 = cov[tile * 4 + 0];
    const float s01 = cov[tile * 4 + 1];
    const float s10 = cov[tile * 4 + 2];
    const float s11 = cov[tile * 4 + 3];
    const float det = s00 * s11 - s01 * s10 + EPS;
    const float inv_det = 1.0f / det;
    const float c_xx = -0.5f *  s11 * inv_det;
    const float c_xy =  0.5f * (s01 + s10) * inv_det;
    const float c_yy = -0.5f *  s00 * inv_det;

    auto e_at = [&](int idx) -> float {
        const float dy = (float)(idx >> 6) - my;   // row = y
        const float dx = (float)(idx & 63) - mx;   // col = x
        return __expf((c_xx * dx + c_xy * dy) * dx + c_yy * dy * dy);
    };

    // ---- Pass A: compute exp once per pixel, stash in LDS, accumulate sum. ----
    float esum = 0.0f;
    #pragma unroll
    for (int k = 0; k < PPT / 4; k++) {
        const int v = k * BLK + t;
        const int base = v * 4;
        float4 e4;
        e4.x = e_at(base + 0);
        e4.y = e_at(base + 1);
        e4.z = e_at(base + 2);
        e4.w = e_at(base + 3);
        reinterpret_cast<float4*>(e_lds)[v] = e4;   // ds_write_b128, stride-1
        esum += (e4.x + e4.y) + (e4.z + e4.w);
    }

    const float S = block_reduce_sum(esum, sbuf);  // barrier also publishes e_lds
    const float invS = 1.0f / S;

    // ---- Pass B: coalesced hm read + LDS readback; one log per pixel. ----
    auto kterm = [&](float hvi, float e) -> float {
        const float pr = e * invS + EPS;
        // xlogy(hm,hm) - hm*log(pr+EPS) == hm * log(hm / (pr+EPS)) for hm>0
        return (hvi > 0.0f) ? hvi * __logf(__fdividef(hvi, pr)) : 0.0f;
    };

    float kl = 0.0f;
    #pragma unroll
    for (int k = 0; k < PPT / 4; k++) {
        const int v = k * BLK + t;
        const float4 h4 = reinterpret_cast<const float4*>(h)[v];
        const float4 e4 = reinterpret_cast<const float4*>(e_lds)[v];  // ds_read_b128
        kl += kterm(h4.x, e4.x);
        kl += kterm(h4.y, e4.y);
        kl += kterm(h4.z, e4.z);
        kl += kterm(h4.w, e4.w);
    }

    const float tile_sum = block_reduce_sum(kl, sbuf);
    if (threadIdx.x == 0) {
        atomicAdd(out, tile_sum * (1.0f / (float)NTILE));
    }
}

extern "C" void kernel_launch(void* const* d_in, const int* in_sizes, int n_in,
                              void* d_out, int out_size, void* d_ws, size_t ws_size,
                              hipStream_t stream) {
    const float* hm    = (const float*)d_in[0];
    const float* means = (const float*)d_in[1];
    const float* cov   = (const float*)d_in[2];
    float* out = (float*)d_out;

    hipMemsetAsync(out, 0, sizeof(float), stream);
    gauss_kld_kernel<<<NTILE, BLK, 0, stream>>>(hm, means, cov, out);
}

// Round 6
// 116.016 us; speedup vs baseline: 1.2702x; 1.2702x over previous
//
#include <hip/hip_runtime.h>
#include <math.h>

#define EPS 1e-5f

constexpr int NPIX  = 4096;   // 64x64 pixels per tile
constexpr int NTILE = 4352;   // 64*68 tiles
constexpr int BLK   = 256;
constexpr int PPT   = NPIX / BLK; // 16 pixels per thread

// Block-wide sum reduction (256 threads = 4 waves of 64).
__device__ __forceinline__ float block_reduce_sum(float v, float* sbuf) {
    __syncthreads();
    #pragma unroll
    for (int o = 32; o > 0; o >>= 1) v += __shfl_down(v, o, 64);
    const int lane = threadIdx.x & 63;
    const int wid  = threadIdx.x >> 6;
    if (lane == 0) sbuf[wid] = v;
    __syncthreads();
    if (threadIdx.x == 0) sbuf[4] = sbuf[0] + sbuf[1] + sbuf[2] + sbuf[3];
    __syncthreads();
    return sbuf[4];
}

// Kernel 1: one WAVE per tile. lane = column -> dx constant per lane,
// per pixel: 2 fma + 1 exp. Wave shuffle reduce; no LDS, no barrier.
__global__ __launch_bounds__(BLK)
void norm_kernel(const float* __restrict__ means,
                 const float* __restrict__ cov,
                 float* __restrict__ S_arr,
                 float* __restrict__ logS_arr) {
    const int lane = threadIdx.x & 63;
    const int tile = blockIdx.x * 4 + (threadIdx.x >> 6);

    const float mx  = means[tile * 2 + 0];
    const float my  = means[tile * 2 + 1];
    const float s00 = cov[tile * 4 + 0];
    const float s01 = cov[tile * 4 + 1];
    const float s10 = cov[tile * 4 + 2];
    const float s11 = cov[tile * 4 + 3];
    const float det = s00 * s11 - s01 * s10 + EPS;
    const float inv_det = 1.0f / det;
    const float cxx = -0.5f *  s11 * inv_det;
    const float cxy =  0.5f * (s01 + s10) * inv_det;
    const float cyy = -0.5f *  s00 * inv_det;

    const float dx = (float)lane - mx;
    const float qx = cxx * dx * dx;   // lane-constant part
    const float bx = cxy * dx;

    float s = 0.0f;
    #pragma unroll
    for (int y = 0; y < 64; y++) {
        const float dy = (float)y - my;
        const float lp = qx + (bx + cyy * dy) * dy;
        s += __expf(lp);
    }
    #pragma unroll
    for (int o = 32; o > 0; o >>= 1) s += __shfl_down(s, o, 64);
    if (lane == 0) {
        S_arr[tile]    = s;
        logS_arr[tile] = __logf(s);
    }
}

// Kernel 2: one block per tile; S precomputed -> pure streaming, no mid barrier.
// log(pr + EPS) = log(e + EPS*S) - log(S); fold logS out of the pixel loop.
__global__ __launch_bounds__(BLK)
void kl_kernel(const float* __restrict__ hm,
               const float* __restrict__ means,
               const float* __restrict__ cov,
               const float* __restrict__ S_arr,
               const float* __restrict__ logS_arr,
               float* __restrict__ partial) {
    const int tile = blockIdx.x;
    const float* __restrict__ h = hm + (size_t)tile * NPIX;
    const int t = threadIdx.x;

    // Issue all heatmap loads up front (independent of everything below).
    const float4* __restrict__ h4p = reinterpret_cast<const float4*>(h);
    const float4 hv0 = h4p[0 * BLK + t];
    const float4 hv1 = h4p[1 * BLK + t];
    const float4 hv2 = h4p[2 * BLK + t];
    const float4 hv3 = h4p[3 * BLK + t];

    const float mx  = means[tile * 2 + 0];
    const float my  = means[tile * 2 + 1];
    const float s00 = cov[tile * 4 + 0];
    const float s01 = cov[tile * 4 + 1];
    const float s10 = cov[tile * 4 + 2];
    const float s11 = cov[tile * 4 + 3];
    const float det = s00 * s11 - s01 * s10 + EPS;
    const float inv_det = 1.0f / det;
    const float cxx = -0.5f *  s11 * inv_det;
    const float cxy =  0.5f * (s01 + s10) * inv_det;
    const float cyy = -0.5f *  s00 * inv_det;

    const float S    = S_arr[tile];
    const float logS = logS_arr[tile];
    const float E    = EPS * S;

    float kl = 0.0f;
    float hs = 0.0f;

    auto pixel = [&](float hv, int idx) {
        const float dy = (float)(idx >> 6) - my;
        const float dx = (float)(idx & 63) - mx;
        const float lp = (cxx * dx + cxy * dy) * dx + cyy * dy * dy;
        const float u  = __expf(lp) + E;           // (pr+EPS)*S
        if (hv > 0.0f) {
            kl += hv * __logf(__fdividef(hv, u));  // hv*(log hv - log u)
            hs += hv;
        }
    };

    #define GROUP(h4v, kk)                         \
        {                                          \
            const int base = ((kk) * BLK + t) * 4; \
            pixel(h4v.x, base + 0);                \
            pixel(h4v.y, base + 1);                \
            pixel(h4v.z, base + 2);                \
            pixel(h4v.w, base + 3);                \
        }
    GROUP(hv0, 0)
    GROUP(hv1, 1)
    GROUP(hv2, 2)
    GROUP(hv3, 3)
    #undef GROUP

    __shared__ float sbuf[8];
    const float kl_sum = block_reduce_sum(kl, sbuf);
    const float hs_sum = block_reduce_sum(hs, sbuf);
    if (threadIdx.x == 0) partial[tile] = kl_sum + logS * hs_sum;
}

__global__ __launch_bounds__(BLK)
void reduce_kernel(const float* __restrict__ partial,
                   float* __restrict__ out) {
    float s = 0.0f;
    for (int i = threadIdx.x; i < NTILE; i += BLK) s += partial[i];
    __shared__ float sbuf[8];
    const float tot = block_reduce_sum(s, sbuf);
    if (threadIdx.x == 0) out[0] = tot / (float)NTILE;
}

extern "C" void kernel_launch(void* const* d_in, const int* in_sizes, int n_in,
                              void* d_out, int out_size, void* d_ws, size_t ws_size,
                              hipStream_t stream) {
    const float* hm    = (const float*)d_in[0];
    const float* means = (const float*)d_in[1];
    const float* cov   = (const float*)d_in[2];
    float* out = (float*)d_out;

    float* S_arr    = (float*)d_ws;
    float* logS_arr = S_arr + NTILE;
    float* partial  = logS_arr + NTILE;

    norm_kernel<<<NTILE / 4, BLK, 0, stream>>>(means, cov, S_arr, logS_arr);
    kl_kernel<<<NTILE, BLK, 0, stream>>>(hm, means, cov, S_arr, logS_arr, partial);
    reduce_kernel<<<1, BLK, 0, stream>>>(partial, out);
}